// Round 17
// baseline (453.106 us; speedup 1.0000x reference)
//
#include <hip/hip_runtime.h>

// Problem constants: B=4096, K=16, H=32, HM=128, STEPS=8
#define OFF_MS  524288
#define OFF_CS  557056
#define OFF_IP  1081344
#define OFF_CUM 1179648
#define OFF_EPS 1183744

#define HSTR 136   // padded bf16 row stride (272B -> 2-way banks)
#define BSTR 40    // padded bf16 row stride (80B)

// d_ws layout (u16): bf16 weights transposed to [n][k]
#define WA_PTP 0        // ptp_w2T [32][128]
#define WB_PTA 4096     // pta_w1T [128][32]
#define WC_PTA 8192     // pta_w2T [32][128]
#define WA_CAP 12288    // cap_w2T [32][128]
#define WB_CAA 16384    // caa_w1T [128][32]
#define WC_CAA 20480    // caa_w2T [32][128]

struct Params {
  const float *knn, *query, *fw1, *fb1, *fw2, *fb2, *fw3, *fb3, *qkv_w,
    *ptp_w1, *ptp_b1, *ptp_w2, *ptp_b2, *pta_w1, *pta_b1, *pta_w2, *pta_b2,
    *caq_w, *caq_b, *cak_w, *cak_b, *cav_w, *cav_b,
    *cap_w1, *cap_b1, *cap_w2, *cap_b2, *caa_w1, *caa_b1, *caa_w2, *caa_b2,
    *im_w1, *im_b1, *im_w2, *im_b2, *im_w3, *im_b3,
    *ep_w1, *ep_b1, *ep_w2, *ep_b2, *ep_w3, *ep_b3;
  float *o_ld, *o_ms, *o_cs, *o_ip, *o_cum, *o_eps;
};
static_assert(sizeof(Params) == 49 * sizeof(void*), "Params layout");

typedef float f32x4 __attribute__((ext_vector_type(4)));
typedef unsigned short u16x8 __attribute__((ext_vector_type(8)));

__device__ __forceinline__ unsigned short f2b(float x) {  // fp32->bf16 RNE
  unsigned u = __float_as_uint(x);
  u += 0x7fffu + ((u >> 16) & 1u);
  return (unsigned short)(u >> 16);
}
__device__ __forceinline__ unsigned pack2(float lo, float hi) {
  return (unsigned)f2b(lo) | ((unsigned)f2b(hi) << 16);
}

#define MFMA(acc, a, bb) \
  asm volatile("s_nop 2\n\tv_mfma_f32_16x16x32_bf16 %0, %1, %2, %0" \
               : "+v"(acc) : "v"(a), "v"(bb))
#define MFMA_FENCE(acc) asm volatile("s_nop 7\n\ts_nop 7" : "+v"(acc))

// Prep: transpose+convert the 6 MFMA weight matrices into d_ws (once/launch).
__global__ void prep_kernel(Params p, unsigned short* ws) {
  const int t = blockIdx.x * 256 + threadIdx.x;  // 0..4095
  const int n = t >> 7, k = t & 127;
  ws[WA_PTP + t] = f2b(p.ptp_w2[k * 32 + n]);
  ws[WC_PTA + t] = f2b(p.pta_w2[k * 32 + n]);
  ws[WA_CAP + t] = f2b(p.cap_w2[k * 32 + n]);
  ws[WC_CAA + t] = f2b(p.caa_w2[k * 32 + n]);
  const int n2 = t >> 5, k2 = t & 31;
  ws[WB_PTA + t] = f2b(p.pta_w1[k2 * 128 + n2]);
  ws[WB_CAA + t] = f2b(p.caa_w1[k2 * 128 + n2]);
}

// WAVE-PER-BATCH (round 16, 452us, 120 VGPR, no spill) with the occupancy
// cap lifted: (64,2) capped residency at 2 waves/SIMD (23% occ) while the
// kernel uses only 120 VGPR. (64,4) = VGPR budget 512/4=128 (still fits)
// and 4 waves/SIMD -> 16 independent batch-waves/CU. All waves barrier-free
// and independent -> latency-bound kernel should scale ~linearly.
__launch_bounds__(64, 4)
__global__ void puray_kernel(Params p, const unsigned short* ws) {
  const int b = blockIdx.x;
  const int l = threadIdx.x;
  const int ln16 = l & 15, kg = l >> 4, k0 = kg * 8;

  __shared__ __align__(16) unsigned short s_hvb[16 * HSTR];   // hv A-operand
  __shared__ __align__(16) unsigned short s_hidb[16 * HSTR];  // G2/secC out
  __shared__ __align__(16) unsigned short s_simb[16 * BSTR];
  __shared__ float s_feats[512], s_v[512];
  __shared__ float s_u[1024];    // A: h1|h2 ; B/C: q|k ; D: kk|vvb
  __shared__ float s_coords[48], s_relv[48], s_reld[16];
  __shared__ float s_qry[3], s_op[3], s_qq[32], s_ca[32];
  __shared__ float s_cum;

  if (l < 48) s_coords[l] = p.knn[b * 48 + l];
  else if (l < 51) s_qry[l - 48] = p.query[b * 3 + (l - 48)];
  else if (l == 51) s_cum = 0.f;
  else if (l < 55) s_op[l - 52] = 0.f;
  __syncthreads();

  // ---- Phase A: feats (h1 -> s_u[0:512], h2 -> s_u[512:1024]) ----
  for (int m = 0; m < 8; ++m) {
    const int idx = l + 64 * m, pp = idx >> 5, jj = idx & 31;
    float a = p.fb1[jj];
    for (int c = 0; c < 3; ++c) a = fmaf(s_coords[pp * 3 + c], p.fw1[c * 32 + jj], a);
    s_u[idx] = fmaxf(a, 0.f);
  }
  for (int m = 0; m < 8; ++m) {
    const int idx = l + 64 * m, pp = idx >> 5, jj = idx & 31;
    float a = p.fb2[jj];
    for (int i = 0; i < 32; ++i) a = fmaf(s_u[pp * 32 + i], p.fw2[i * 32 + jj], a);
    s_u[512 + idx] = fmaxf(a, 0.f);
  }
  for (int m = 0; m < 8; ++m) {
    const int idx = l + 64 * m, pp = idx >> 5, jj = idx & 31;
    float a = p.fb3[jj];
    for (int i = 0; i < 32; ++i) a = fmaf(s_u[512 + pp * 32 + i], p.fw3[i * 32 + jj], a);
    s_feats[idx] = a;
  }
  // ---- Phase B: qkv -> s_u (q|k) + s_v ----
  for (int m = 0; m < 24; ++m) {
    const int idx = l + 64 * m, pp = idx / 96, o = idx % 96;
    float a = 0.f;
    for (int i = 0; i < 32; ++i) a = fmaf(s_feats[pp * 32 + i], p.qkv_w[i * 96 + o], a);
    if (o < 32) s_u[pp * 32 + o] = a;
    else if (o < 64) s_u[512 + pp * 32 + o - 32] = a;
    else s_v[pp * 32 + o - 64] = a;
  }

  // ---- Phase C: one i-row at a time, all within the wave ----
  {
    const float* w1c = p.ptp_w1;
    const float* b1c = p.ptp_b1;
    const float* b2c = p.ptp_b2;
    const float* bh1 = p.pta_b1;
    const float* bh2 = p.pta_b2;
    const unsigned short* wsc = ws;
    for (int i = 0; i < 16; ++i) {
      asm volatile("" : "+s"(w1c), "+s"(b1c), "+s"(b2c), "+s"(bh1), "+s"(bh2), "+s"(wsc));
      const float c0 = s_coords[i * 3 + 0] - s_coords[ln16 * 3 + 0];
      const float c1 = s_coords[i * 3 + 1] - s_coords[ln16 * 3 + 1];
      const float c2 = s_coords[i * 3 + 2] - s_coords[ln16 * 3 + 2];
      // hv -> s_hvb (row ln16, d = kg*32 .. kg*32+31; 2 live values only)
      for (int x = 0; x < 32; x += 2) {
        const int d = kg * 32 + x;
        const float h0v = fmaxf(fmaf(c0, w1c[d],
                           fmaf(c1, w1c[128 + d],
                           fmaf(c2, w1c[256 + d], b1c[d]))), 0.f);
        const float h1v = fmaxf(fmaf(c0, w1c[d + 1],
                           fmaf(c1, w1c[128 + d + 1],
                           fmaf(c2, w1c[256 + d + 1], b1c[d + 1]))), 0.f);
        ((unsigned*)s_hvb)[(ln16 * HSTR + d) >> 1] = pack2(h0v, h1v);
      }
      f32x4 rpe0, rpe1;
      {  // G1 nb=0: rpe = hv @ ptp_w2 + b2 (A from LDS)
        const int n = ln16;
        const float bias = b2c[n];
        f32x4 acc = {bias, bias, bias, bias};
#pragma unroll
        for (int kk = 0; kk < 4; ++kk) {
          const u16x8 a = *(const u16x8*)&s_hvb[ln16 * HSTR + kk * 32 + k0];
          MFMA(acc, a, *(const u16x8*)&wsc[WA_PTP + n * 128 + kk * 32 + k0]);
        }
        MFMA_FENCE(acc);
        rpe0 = acc;
#pragma unroll
        for (int r2 = 0; r2 < 4; ++r2) {
          const int j = kg * 4 + r2;
          s_simb[j * BSTR + n] = f2b(s_u[i * 32 + n] - s_u[512 + j * 32 + n] + acc[r2]);
        }
      }
      {  // G1 nb=1
        const int n = 16 + ln16;
        const float bias = b2c[n];
        f32x4 acc = {bias, bias, bias, bias};
#pragma unroll
        for (int kk = 0; kk < 4; ++kk) {
          const u16x8 a = *(const u16x8*)&s_hvb[ln16 * HSTR + kk * 32 + k0];
          MFMA(acc, a, *(const u16x8*)&wsc[WA_PTP + n * 128 + kk * 32 + k0]);
        }
        MFMA_FENCE(acc);
        rpe1 = acc;
#pragma unroll
        for (int r2 = 0; r2 < 4; ++r2) {
          const int j = kg * 4 + r2;
          s_simb[j * BSTR + n] = f2b(s_u[i * 32 + n] - s_u[512 + j * 32 + n] + acc[r2]);
        }
      }
      {  // G2: hid[16][128] = relu(simin @ pta_w1 + b1)
        const u16x8 a2 = *(const u16x8*)&s_simb[ln16 * BSTR + k0];
#pragma unroll
        for (int j2 = 0; j2 < 8; ++j2) {
          const int n = j2 * 16 + ln16;
          const float bias = bh1[n];
          f32x4 acc = {bias, bias, bias, bias};
          MFMA(acc, a2, *(const u16x8*)&wsc[WB_PTA + n * 32 + k0]);
          MFMA_FENCE(acc);
#pragma unroll
          for (int r2 = 0; r2 < 4; ++r2)
            s_hidb[(kg * 4 + r2) * HSTR + n] = f2b(fmaxf(acc[r2], 0.f));
        }
      }
      // G3 + fused softmax -> feats[i]
#pragma unroll
      for (int nb = 0; nb < 2; ++nb) {
        const int n = nb * 16 + ln16;
        const float bias = bh2[n];
        f32x4 acc = {bias, bias, bias, bias};
#pragma unroll
        for (int kk = 0; kk < 4; ++kk) {
          const u16x8 a3 = *(const u16x8*)&s_hidb[ln16 * HSTR + kk * 32 + k0];
          MFMA(acc, a3, *(const u16x8*)&wsc[WC_PTA + n * 128 + kk * 32 + k0]);
        }
        MFMA_FENCE(acc);
        const f32x4 rp = nb ? rpe1 : rpe0;
        float mx = fmaxf(fmaxf(acc[0], acc[1]), fmaxf(acc[2], acc[3]));
        mx = fmaxf(mx, __shfl_xor(mx, 16));
        mx = fmaxf(mx, __shfl_xor(mx, 32));
        float sum = 0.f, o = 0.f;
#pragma unroll
        for (int r2 = 0; r2 < 4; ++r2) {
          const int j = kg * 4 + r2;
          const float e = __expf(acc[r2] - mx);
          sum += e;
          o = fmaf(e, s_v[j * 32 + n] + rp[r2], o);
        }
        sum += __shfl_xor(sum, 16); o += __shfl_xor(o, 16);
        sum += __shfl_xor(sum, 32); o += __shfl_xor(o, 32);
        if (kg == 0) s_feats[i * 32 + n] = o / sum;
      }
    }
  }

  // ---- kk / vvb (overwrite q|k in s_u) ----
  for (int m = 0; m < 8; ++m) {
    const int idx = l + 64 * m, k = idx >> 5, h = idx & 31;
    float akk = p.cak_b[h], avv = p.cav_b[h];
    for (int i = 0; i < 32; ++i) {
      const float f = s_feats[k * 32 + i];
      akk = fmaf(f, p.cak_w[i * 32 + h], akk);
      avv = fmaf(f, p.cav_w[i * 32 + h], avv);
    }
    s_u[k * 32 + h] = akk;
    s_u[512 + k * 32 + h] = avv;
  }

  // ---- Phase D: 8 march steps + epilogue, all within the wave ----
  {
    const float* w1d = p.cap_w1;
    const float* b1d = p.cap_b1;
    const float* b2d = p.cap_b2;
    const float* bc1 = p.caa_b1;
    const float* bc2 = p.caa_b2;
    const float* fw1 = p.fw1; const float* fw2 = p.fw2; const float* fw3 = p.fw3;
    const float* cqw = p.caq_w;
    const float* iw1 = p.im_w1; const float* iw2 = p.im_w2; const float* iw3 = p.im_w3;
    const unsigned short* wsd = ws;
    for (int s = 0; s <= 8; ++s) {
      asm volatile("" : "+s"(w1d), "+s"(b1d), "+s"(b2d), "+s"(bc1), "+s"(bc2), "+s"(wsd));
      asm volatile("" : "+s"(fw1), "+s"(fw2), "+s"(fw3), "+s"(cqw), "+s"(iw1), "+s"(iw2), "+s"(iw3));
      float rv0 = 0.f, rv1 = 0.f, rv2 = 0.f;
      if (s < 8 && l < 16) {  // rel + o_ld
        const float r0 = s_coords[l * 3 + 0] - s_op[0];
        const float r1 = s_coords[l * 3 + 1] - s_op[1];
        const float r2 = s_coords[l * 3 + 2] - s_op[2];
        const float rd = sqrtf(r0 * r0 + r1 * r1 + r2 * r2);
        const float inv = 1.f / rd;
        rv0 = r0 * inv; rv1 = r1 * inv; rv2 = r2 * inv;
        s_reld[l] = rd;
        s_relv[l * 3 + 0] = rv0; s_relv[l * 3 + 1] = rv1; s_relv[l * 3 + 2] = rv2;
        p.o_ld[b * 128 + s * 16 + l] = rd;
      }
      // secA: pe-hidden hv -> s_hvb (row ln16, d = kg*32..+31)
      {
        float c0, c1, c2;
        if (s < 8) {
          c0 = s_coords[ln16 * 3 + 0] - s_op[0];
          c1 = s_coords[ln16 * 3 + 1] - s_op[1];
          c2 = s_coords[ln16 * 3 + 2] - s_op[2];
        } else {
          const float rd = s_reld[ln16];
          c0 = s_relv[ln16 * 3 + 0] * rd; c1 = s_relv[ln16 * 3 + 1] * rd; c2 = s_relv[ln16 * 3 + 2] * rd;
        }
        for (int x = 0; x < 32; x += 2) {
          const int d = kg * 32 + x;
          const float h0v = fmaxf(fmaf(c0, w1d[d],
                             fmaf(c1, w1d[128 + d],
                             fmaf(c2, w1d[256 + d], b1d[d]))), 0.f);
          const float h1v = fmaxf(fmaf(c0, w1d[d + 1],
                             fmaf(c1, w1d[128 + d + 1],
                             fmaf(c2, w1d[256 + d + 1], b1d[d + 1]))), 0.f);
          ((unsigned*)s_hvb)[(ln16 * HSTR + d) >> 1] = pack2(h0v, h1v);
        }
      }
      {  // qq chain (all lanes, width-32 shuffles; halves duplicate)
        const int h = l & 31;
        float opc0, opc1, opc2;
        if (s < 8) {
          const float cum = s_cum;
          opc0 = s_qry[0] * cum; opc1 = s_qry[1] * cum; opc2 = s_qry[2] * cum;
        } else {
          opc0 = s_op[0]; opc1 = s_op[1]; opc2 = s_op[2];
        }
        float v1 = fmaxf(fmaf(opc0, fw1[h],
                      fmaf(opc1, fw1[32 + h],
                      fmaf(opc2, fw1[64 + h], p.fb1[h]))), 0.f);
        float a = p.fb2[h];
        for (int i2 = 0; i2 < 32; ++i2) a = fmaf(__shfl(v1, i2, 32), fw2[i2 * 32 + h], a);
        const float v2 = fmaxf(a, 0.f);
        a = p.fb3[h];
        for (int i2 = 0; i2 < 32; ++i2) a = fmaf(__shfl(v2, i2, 32), fw3[i2 * 32 + h], a);
        const float opf = a;
        a = p.caq_b[h];
        for (int i2 = 0; i2 < 32; ++i2) a = fmaf(__shfl(opf, i2, 32), cqw[i2 * 32 + h], a);
        if (l < 32) s_qq[h] = a;
      }
      f32x4 pe0, pe1;
      {  // secB nb=0: pe = hv @ cap_w2 + b2 (A from LDS)
        const int n = ln16;
        const float bias = b2d[n];
        f32x4 acc = {bias, bias, bias, bias};
#pragma unroll
        for (int kk = 0; kk < 4; ++kk) {
          const u16x8 a = *(const u16x8*)&s_hvb[ln16 * HSTR + kk * 32 + k0];
          MFMA(acc, a, *(const u16x8*)&wsd[WA_CAP + n * 128 + kk * 32 + k0]);
        }
        MFMA_FENCE(acc);
        pe0 = acc;
#pragma unroll
        for (int r2 = 0; r2 < 4; ++r2) {
          const int row = kg * 4 + r2;
          s_simb[row * BSTR + n] = f2b(s_qq[n] - s_u[row * 32 + n] + acc[r2]);
        }
      }
      {  // secB nb=1
        const int n = 16 + ln16;
        const float bias = b2d[n];
        f32x4 acc = {bias, bias, bias, bias};
#pragma unroll
        for (int kk = 0; kk < 4; ++kk) {
          const u16x8 a = *(const u16x8*)&s_hvb[ln16 * HSTR + kk * 32 + k0];
          MFMA(acc, a, *(const u16x8*)&wsd[WA_CAP + n * 128 + kk * 32 + k0]);
        }
        MFMA_FENCE(acc);
        pe1 = acc;
#pragma unroll
        for (int r2 = 0; r2 < 4; ++r2) {
          const int row = kg * 4 + r2;
          s_simb[row * BSTR + n] = f2b(s_qq[n] - s_u[row * 32 + n] + acc[r2]);
        }
      }
      {  // secC: hid = relu(ain @ caa_w1 + b1)
        const u16x8 a2 = *(const u16x8*)&s_simb[ln16 * BSTR + k0];
#pragma unroll
        for (int j2 = 0; j2 < 8; ++j2) {
          const int n = j2 * 16 + ln16;
          const float bias = bc1[n];
          f32x4 acc = {bias, bias, bias, bias};
          MFMA(acc, a2, *(const u16x8*)&wsd[WB_CAA + n * 32 + k0]);
          MFMA_FENCE(acc);
#pragma unroll
          for (int r2 = 0; r2 < 4; ++r2)
            s_hidb[(kg * 4 + r2) * HSTR + n] = f2b(fmaxf(acc[r2], 0.f));
        }
      }
      // secD + in-register softmax -> ca0/ca1
      float ca0 = 0.f, ca1 = 0.f;
#pragma unroll
      for (int nb = 0; nb < 2; ++nb) {
        const int n = nb * 16 + ln16;
        const float bias = bc2[n];
        f32x4 acc = {bias, bias, bias, bias};
#pragma unroll
        for (int kk = 0; kk < 4; ++kk) {
          const u16x8 a3 = *(const u16x8*)&s_hidb[ln16 * HSTR + kk * 32 + k0];
          MFMA(acc, a3, *(const u16x8*)&wsd[WC_CAA + n * 128 + kk * 32 + k0]);
        }
        MFMA_FENCE(acc);
        const f32x4 rp = nb ? pe1 : pe0;
        float mx = fmaxf(fmaxf(acc[0], acc[1]), fmaxf(acc[2], acc[3]));
        mx = fmaxf(mx, __shfl_xor(mx, 16));
        mx = fmaxf(mx, __shfl_xor(mx, 32));
        float sum = 0.f, o = 0.f;
#pragma unroll
        for (int r2 = 0; r2 < 4; ++r2) {
          const int row = kg * 4 + r2;
          const float e = __expf(acc[r2] - mx);
          sum += e;
          o = fmaf(e, s_u[512 + row * 32 + n] + rp[r2], o);
        }
        sum += __shfl_xor(sum, 16); o += __shfl_xor(o, 16);
        sum += __shfl_xor(sum, 32); o += __shfl_xor(o, 32);
        if (nb == 0) ca0 = o / sum; else ca1 = o / sum;
      }
      if (kg == 0) { s_ca[ln16] = ca0; s_ca[16 + ln16] = ca1; }
      {  // im / ep chain (width-32; halves duplicate; writes guarded)
        const int h = l & 31;
        const float cav = s_ca[h];
        if (s < 8) {
          float a = p.im_b1[h];
          for (int i2 = 0; i2 < 32; ++i2) a = fmaf(__shfl(cav, i2, 32), iw1[i2 * 32 + h], a);
          const float m1 = fmaxf(a, 0.f);
          a = p.im_b2[h];
          for (int i2 = 0; i2 < 32; ++i2) a = fmaf(__shfl(m1, i2, 32), iw2[i2 * 32 + h], a);
          const float m2 = fmaxf(a, 0.f);
          float p0 = m2 * iw3[h * 3 + 0];
          float p1 = m2 * iw3[h * 3 + 1];
          float p2 = m2 * iw3[h * 3 + 2];
#pragma unroll
          for (int m = 1; m < 32; m <<= 1) {
            p0 += __shfl_xor(p0, m, 32);
            p1 += __shfl_xor(p1, m, 32);
            p2 += __shfl_xor(p2, m, 32);
          }
          p0 += p.im_b3[0]; p1 += p.im_b3[1]; p2 += p.im_b3[2];
          const float step = sqrtf(p0 * p0 + p1 * p1 + p2 * p2);
          const float cum = s_cum;
          const float opc0 = s_qry[0] * cum, opc1 = s_qry[1] * cum, opc2 = s_qry[2] * cum;
          const float inv = 1.f / step;
          const float tg0 = p0 * inv, tg1 = p1 * inv, tg2 = p2 * inv;
          if (l == 0) {
            p.o_ms[b * 8 + s] = step;
            p.o_ip[(b * 8 + s) * 3 + 0] = opc0 + p0;
            s_op[0] = opc0 + s_qry[0] * step;
          } else if (l == 1) {
            p.o_ip[(b * 8 + s) * 3 + 1] = opc1 + p1;
            s_op[1] = opc1 + s_qry[1] * step;
          } else if (l == 2) {
            p.o_ip[(b * 8 + s) * 3 + 2] = opc2 + p2;
            s_op[2] = opc2 + s_qry[2] * step;
          } else if (l == 3) {
            s_cum = cum + step;
          }
          if (l < 16) {
            p.o_cs[b * 128 + s * 16 + l] = tg0 * rv0 + tg1 * rv1 + tg2 * rv2;
          }
        } else {
          float a = p.ep_b1[h];
          for (int i2 = 0; i2 < 32; ++i2) a = fmaf(__shfl(cav, i2, 32), p.ep_w1[i2 * 32 + h], a);
          a = fmaf(s_qry[0], p.ep_w1[1024 + h], a);
          a = fmaf(s_qry[1], p.ep_w1[1056 + h], a);
          a = fmaf(s_qry[2], p.ep_w1[1088 + h], a);
          const float e1 = fmaxf(a, 0.f);
          a = p.ep_b2[h];
          for (int i2 = 0; i2 < 32; ++i2) a = fmaf(__shfl(e1, i2, 32), p.ep_w2[i2 * 32 + h], a);
          const float e2 = fmaxf(a, 0.f);
          float pp = e2 * p.ep_w3[h];
#pragma unroll
          for (int m = 1; m < 32; m <<= 1) pp += __shfl_xor(pp, m, 32);
          if (l == 0) {
            p.o_eps[b] = pp + p.ep_b3[0];
            p.o_cum[b] = s_cum;
          }
        }
      }
    }
  }
}

extern "C" void kernel_launch(void* const* d_in, const int* in_sizes, int n_in,
                              void* d_out, int out_size, void* d_ws, size_t ws_size,
                              hipStream_t stream) {
  Params p;
  const float** f = (const float**)(void*)&p;
  for (int i = 0; i < 43; ++i) f[i] = (const float*)d_in[i];
  float* out = (float*)d_out;
  p.o_ld  = out;
  p.o_ms  = out + OFF_MS;
  p.o_cs  = out + OFF_CS;
  p.o_ip  = out + OFF_IP;
  p.o_cum = out + OFF_CUM;
  p.o_eps = out + OFF_EPS;
  unsigned short* ws = (unsigned short*)d_ws;
  prep_kernel<<<dim3(16), dim3(256), 0, stream>>>(p, ws);
  puray_kernel<<<dim3(4096), dim3(64), 0, stream>>>(p, ws);
}